// Round 1
// baseline (616.114 us; speedup 1.0000x reference)
//
#include <hip/hip_runtime.h>

#define NB 4
#define C  256
#define NN 4096

typedef _Float16 half8  __attribute__((ext_vector_type(8)));
typedef _Float16 half4_t __attribute__((ext_vector_type(4)));
typedef float    f32x4  __attribute__((ext_vector_type(4)));

static __device__ __forceinline__ f32x4 mfma16(half8 a, half8 b, f32x4 c) {
    return __builtin_amdgcn_mfma_f32_16x16x32_f16(a, b, c, 0, 0, 0);
}

// ---------------------------------------------------------------------------
// Kernel 1: QKV projection (split-f16 for accuracy) + relu(fea) copy to out.
//   Qt[b][n][t], Kt[b][n][t]  (N x 256, t contiguous)  f16
//   Vp[b][o][n]               (256 x N, n contiguous)  f16
//   out[b][256+c][n] = relu(fea[b][c][n])
// Block: 32 n-columns of one batch. 256 threads (4 waves).
// ---------------------------------------------------------------------------
__global__ __launch_bounds__(256) void proj_kernel(
    const float* __restrict__ fea, const float* __restrict__ Wq,
    const float* __restrict__ Wk, const float* __restrict__ Wv,
    _Float16* __restrict__ Qt, _Float16* __restrict__ Kt,
    _Float16* __restrict__ Vp, float* __restrict__ out)
{
    const int lin = blockIdx.x + gridDim.x * blockIdx.y;
    const int xcd = lin & 7;                 // XCD-aware swizzle: one batch per XCD
    const int b   = xcd >> 1;
    const int nt  = ((lin >> 3) << 1) | (xcd & 1);
    const int n0  = nt * 32;

    __shared__ __align__(16) _Float16 fh[32][264];  // feaT hi  (n x i, i contiguous)
    __shared__ __align__(16) _Float16 fl[32][264];  // feaT lo

    const int tid = threadIdx.x;
    {
        const int nl = tid & 31, rr = tid >> 5;
        const float* feab = fea + (size_t)b * C * NN + n0 + nl;
        float* outb = out + (size_t)b * 2 * C * NN + (size_t)C * NN + n0 + nl;
#pragma unroll
        for (int p = 0; p < 32; ++p) {
            const int i = p * 8 + rr;
            const float v = feab[(size_t)i * NN];
            outb[(size_t)i * NN] = fmaxf(v, 0.f);
            const _Float16 h = (_Float16)v;
            fh[nl][i] = h;
            fl[nl][i] = (_Float16)(v - (float)h);
        }
    }
    __syncthreads();

    const int w = tid >> 6, lane = tid & 63, lr = lane & 15, lg = lane >> 4;

    // ---- Q and K:  D[n(32), t(256)] = sum_i feaT[n][i] * W[t][i]
    //      wave w covers t in [w*64, w*64+64)
    const float* const Ws[2] = {Wq, Wk};
    _Float16* const   Od[2] = {Qt + (size_t)b * NN * C, Kt + (size_t)b * NN * C};
#pragma unroll 1
    for (int qk = 0; qk < 2; ++qk) {
        const float* __restrict__ W = Ws[qk];
        f32x4 acc[2][4];
#pragma unroll
        for (int mi = 0; mi < 2; ++mi)
#pragma unroll
            for (int ni = 0; ni < 4; ++ni) acc[mi][ni] = (f32x4){0.f, 0.f, 0.f, 0.f};

#pragma unroll 1
        for (int kt = 0; kt < 8; ++kt) {
            half8 ah[2], al[2];
#pragma unroll
            for (int mi = 0; mi < 2; ++mi) {
                ah[mi] = *(const half8*)&fh[mi * 16 + lr][kt * 32 + lg * 8];
                al[mi] = *(const half8*)&fl[mi * 16 + lr][kt * 32 + lg * 8];
            }
            half8 bh[4], bl[4];
#pragma unroll
            for (int ni = 0; ni < 4; ++ni) {
                const float* src = W + (size_t)(w * 64 + ni * 16 + lr) * C + kt * 32 + lg * 8;
                const float4 x0 = *(const float4*)src;
                const float4 x1 = *(const float4*)(src + 4);
                const float xs[8] = {x0.x, x0.y, x0.z, x0.w, x1.x, x1.y, x1.z, x1.w};
#pragma unroll
                for (int e = 0; e < 8; ++e) {
                    const _Float16 h = (_Float16)xs[e];
                    bh[ni][e] = h;
                    bl[ni][e] = (_Float16)(xs[e] - (float)h);
                }
            }
#pragma unroll
            for (int mi = 0; mi < 2; ++mi)
#pragma unroll
                for (int ni = 0; ni < 4; ++ni) {
                    acc[mi][ni] = mfma16(ah[mi], bh[ni], acc[mi][ni]);
                    acc[mi][ni] = mfma16(ah[mi], bl[ni], acc[mi][ni]);
                    acc[mi][ni] = mfma16(al[mi], bh[ni], acc[mi][ni]);
                }
        }
        _Float16* dst = Od[qk];
#pragma unroll
        for (int mi = 0; mi < 2; ++mi)
#pragma unroll
            for (int ni = 0; ni < 4; ++ni)
#pragma unroll
                for (int r = 0; r < 4; ++r)
                    dst[(size_t)(n0 + mi * 16 + lg * 4 + r) * C + (w * 64 + ni * 16 + lr)] =
                        (_Float16)acc[mi][ni][r];
    }

    // ---- V:  D[o(256), n(32)] = sum_i Wv[o][i] * fea[i][n]
    //      wave w covers o in [w*64, w*64+64)
    {
        f32x4 acc[4][2];
#pragma unroll
        for (int mi = 0; mi < 4; ++mi)
#pragma unroll
            for (int ni = 0; ni < 2; ++ni) acc[mi][ni] = (f32x4){0.f, 0.f, 0.f, 0.f};

#pragma unroll 1
        for (int kt = 0; kt < 8; ++kt) {
            half8 ah[4], al[4];
#pragma unroll
            for (int mi = 0; mi < 4; ++mi) {
                const float* src = Wv + (size_t)(w * 64 + mi * 16 + lr) * C + kt * 32 + lg * 8;
                const float4 x0 = *(const float4*)src;
                const float4 x1 = *(const float4*)(src + 4);
                const float xs[8] = {x0.x, x0.y, x0.z, x0.w, x1.x, x1.y, x1.z, x1.w};
#pragma unroll
                for (int e = 0; e < 8; ++e) {
                    const _Float16 h = (_Float16)xs[e];
                    ah[mi][e] = h;
                    al[mi][e] = (_Float16)(xs[e] - (float)h);
                }
            }
            half8 bh[2], bl[2];
#pragma unroll
            for (int ni = 0; ni < 2; ++ni) {
                bh[ni] = *(const half8*)&fh[ni * 16 + lr][kt * 32 + lg * 8];
                bl[ni] = *(const half8*)&fl[ni * 16 + lr][kt * 32 + lg * 8];
            }
#pragma unroll
            for (int mi = 0; mi < 4; ++mi)
#pragma unroll
                for (int ni = 0; ni < 2; ++ni) {
                    acc[mi][ni] = mfma16(ah[mi], bh[ni], acc[mi][ni]);
                    acc[mi][ni] = mfma16(ah[mi], bl[ni], acc[mi][ni]);
                    acc[mi][ni] = mfma16(al[mi], bh[ni], acc[mi][ni]);
                }
        }
        _Float16* vb = Vp + (size_t)b * C * NN;
#pragma unroll
        for (int mi = 0; mi < 4; ++mi)
#pragma unroll
            for (int ni = 0; ni < 2; ++ni)
#pragma unroll
                for (int r = 0; r < 4; ++r)
                    vb[(size_t)(w * 64 + mi * 16 + lg * 4 + r) * NN + n0 + ni * 16 + lr] =
                        (_Float16)acc[mi][ni][r];
    }
}

// ---------------------------------------------------------------------------
// Kernel 2: flash attention over key tiles (softmax over keys), fused PV and
// relu, writes out[b][0..255][n].
// Block: 64 query columns of one batch; wave w owns 16 columns.
// ---------------------------------------------------------------------------
__global__ __launch_bounds__(256) void attn_kernel(
    const _Float16* __restrict__ Qt, const _Float16* __restrict__ Kt,
    const _Float16* __restrict__ Vp, float* __restrict__ out)
{
    const int lin = blockIdx.x + gridDim.x * blockIdx.y;
    const int xcd = lin & 7;                 // one batch per XCD (K+V fit 4MB L2)
    const int b   = xcd >> 1;
    const int jt  = ((lin >> 3) << 1) | (xcd & 1);

    const int tid = threadIdx.x;
    const int w = tid >> 6, lane = tid & 63, lr = lane & 15, lg = lane >> 4;
    const int j0 = jt * 64 + w * 16;

    const _Float16* Qb = Qt + (size_t)b * NN * C;
    const _Float16* Kb = Kt + (size_t)b * NN * C;
    const _Float16* Vb = Vp + (size_t)b * C * NN;

    // Q fragments for this wave's 16 columns (kept all K-chunks in regs)
    half8 q[8];
#pragma unroll
    for (int k8 = 0; k8 < 8; ++k8)
        q[k8] = *(const half8*)(Qb + (size_t)(j0 + lr) * C + k8 * 32 + lg * 8);

    f32x4 O[16];
#pragma unroll
    for (int i = 0; i < 16; ++i) O[i] = (f32x4){0.f, 0.f, 0.f, 0.f};
    float m = -1e30f, l = 0.f;

    __shared__ __align__(16) _Float16 P[4][16][72];  // wave-private P tiles [j][i]

#pragma unroll 1
    for (int kt = 0; kt < 64; ++kt) {
        const int i0 = kt * 64;

        // ---- S tile: S[i(64), j(16)] = sum_t K[t,i] Q[t,j]
        f32x4 s[4];
#pragma unroll
        for (int mi = 0; mi < 4; ++mi) s[mi] = (f32x4){0.f, 0.f, 0.f, 0.f};
#pragma unroll
        for (int k8 = 0; k8 < 8; ++k8) {
#pragma unroll
            for (int mi = 0; mi < 4; ++mi) {
                const half8 a = *(const half8*)(Kb + (size_t)(i0 + mi * 16 + lr) * C + k8 * 32 + lg * 8);
                s[mi] = mfma16(a, q[k8], s[mi]);
            }
        }

        // ---- online softmax over rows i (per column j = lane&15)
        float tm = -1e30f;
#pragma unroll
        for (int mi = 0; mi < 4; ++mi)
#pragma unroll
            for (int r = 0; r < 4; ++r) tm = fmaxf(tm, s[mi][r]);
        tm = fmaxf(tm, __shfl_xor(tm, 16, 64));
        tm = fmaxf(tm, __shfl_xor(tm, 32, 64));
        const float mnew  = fmaxf(m, tm);
        const float scale = __expf(m - mnew);
        float ssum = 0.f;
#pragma unroll
        for (int mi = 0; mi < 4; ++mi) {
            half4_t ph;
#pragma unroll
            for (int r = 0; r < 4; ++r) {
                const float p = __expf(s[mi][r] - mnew);
                ssum += p;
                ph[r] = (_Float16)p;
            }
            *(half4_t*)&P[w][lr][mi * 16 + lg * 4] = ph;   // P[j][i] layout
        }
        ssum += __shfl_xor(ssum, 16, 64);
        ssum += __shfl_xor(ssum, 32, 64);
        l = l * scale + ssum;
        m = mnew;
#pragma unroll
        for (int i = 0; i < 16; ++i) O[i] *= scale;

        __syncthreads();   // P write -> P read (cross-lane within wave)

        // ---- PV: O[o(256), j(16)] += V[o,i] P[i,j]
        const half8 pb0 = *(const half8*)&P[w][lr][0 + lg * 8];
        const half8 pb1 = *(const half8*)&P[w][lr][32 + lg * 8];
#pragma unroll
        for (int oi = 0; oi < 16; ++oi) {
            const _Float16* vrow = Vb + (size_t)(oi * 16 + lr) * NN + i0;
            const half8 a0 = *(const half8*)(vrow + lg * 8);
            const half8 a1 = *(const half8*)(vrow + 32 + lg * 8);
            O[oi] = mfma16(a0, pb0, O[oi]);
            O[oi] = mfma16(a1, pb1, O[oi]);
        }
    }

    // ---- epilogue: normalize, relu, store
    const float inv = 1.f / l;
    float* outb = out + (size_t)b * 2 * C * NN + (size_t)(jt * 64 + w * 16 + lr);
#pragma unroll
    for (int oi = 0; oi < 16; ++oi)
#pragma unroll
        for (int r = 0; r < 4; ++r) {
            const int o = oi * 16 + lg * 4 + r;
            outb[(size_t)o * NN] = fmaxf(O[oi][r] * inv, 0.f);
        }
}

// ---------------------------------------------------------------------------
extern "C" void kernel_launch(void* const* d_in, const int* in_sizes, int n_in,
                              void* d_out, int out_size, void* d_ws, size_t ws_size,
                              hipStream_t stream) {
    const float* fea = (const float*)d_in[0];
    const float* Wq  = (const float*)d_in[1];
    const float* Wk  = (const float*)d_in[2];
    const float* Wv  = (const float*)d_in[3];
    float* out = (float*)d_out;

    // workspace: Qt (8MB) | Kt (8MB) | Vp (8MB), all f16
    _Float16* Qt = (_Float16*)d_ws;
    _Float16* Kt = Qt + (size_t)NB * NN * C;
    _Float16* Vp = Kt + (size_t)NB * NN * C;

    proj_kernel<<<dim3(128, 4), 256, 0, stream>>>(fea, Wq, Wk, Wv, Qt, Kt, Vp, out);
    attn_kernel<<<dim3(64, 4), 256, 0, stream>>>(Qt, Kt, Vp, out);
}

// Round 2
// 153.861 us; speedup vs baseline: 4.0043x; 4.0043x over previous
//
#include <hip/hip_runtime.h>

#define NB 4
#define C  256
#define NN 4096
#define TAU 8.0f

typedef _Float16 half8   __attribute__((ext_vector_type(8)));
typedef _Float16 half4_t __attribute__((ext_vector_type(4)));
typedef float    f32x4   __attribute__((ext_vector_type(4)));

static __device__ __forceinline__ f32x4 mfma16(half8 a, half8 b, f32x4 c) {
    return __builtin_amdgcn_mfma_f32_16x16x32_f16(a, b, c, 0, 0, 0);
}

static __device__ __forceinline__ void gld16(const void* g, void* l) {
    __builtin_amdgcn_global_load_lds(
        (const __attribute__((address_space(1))) unsigned int*)g,
        (__attribute__((address_space(3))) unsigned int*)l, 16, 0, 0);
}

// ---------------------------------------------------------------------------
// Kernel 1: QKV projection (split-f16 for accuracy) + relu(fea) copy to out.
//   Qt[b][n][t], Kt[b][n][t]  (N x 256, t contiguous)  f16
//   Vp[b][o][n]               (256 x N, n contiguous)  f16
// (unchanged from round 1 — 39us, not the bottleneck)
// ---------------------------------------------------------------------------
__global__ __launch_bounds__(256) void proj_kernel(
    const float* __restrict__ fea, const float* __restrict__ Wq,
    const float* __restrict__ Wk, const float* __restrict__ Wv,
    _Float16* __restrict__ Qt, _Float16* __restrict__ Kt,
    _Float16* __restrict__ Vp, float* __restrict__ out)
{
    const int lin = blockIdx.x + gridDim.x * blockIdx.y;
    const int xcd = lin & 7;
    const int b   = xcd >> 1;
    const int nt  = ((lin >> 3) << 1) | (xcd & 1);
    const int n0  = nt * 32;

    __shared__ __align__(16) _Float16 fh[32][264];
    __shared__ __align__(16) _Float16 fl[32][264];

    const int tid = threadIdx.x;
    {
        const int nl = tid & 31, rr = tid >> 5;
        const float* feab = fea + (size_t)b * C * NN + n0 + nl;
        float* outb = out + (size_t)b * 2 * C * NN + (size_t)C * NN + n0 + nl;
#pragma unroll
        for (int p = 0; p < 32; ++p) {
            const int i = p * 8 + rr;
            const float v = feab[(size_t)i * NN];
            outb[(size_t)i * NN] = fmaxf(v, 0.f);
            const _Float16 h = (_Float16)v;
            fh[nl][i] = h;
            fl[nl][i] = (_Float16)(v - (float)h);
        }
    }
    __syncthreads();

    const int w = tid >> 6, lane = tid & 63, lr = lane & 15, lg = lane >> 4;

    const float* const Ws[2] = {Wq, Wk};
    _Float16* const   Od[2] = {Qt + (size_t)b * NN * C, Kt + (size_t)b * NN * C};
#pragma unroll 1
    for (int qk = 0; qk < 2; ++qk) {
        const float* __restrict__ W = Ws[qk];
        f32x4 acc[2][4];
#pragma unroll
        for (int mi = 0; mi < 2; ++mi)
#pragma unroll
            for (int ni = 0; ni < 4; ++ni) acc[mi][ni] = (f32x4){0.f, 0.f, 0.f, 0.f};

#pragma unroll 1
        for (int kt = 0; kt < 8; ++kt) {
            half8 ah[2], al[2];
#pragma unroll
            for (int mi = 0; mi < 2; ++mi) {
                ah[mi] = *(const half8*)&fh[mi * 16 + lr][kt * 32 + lg * 8];
                al[mi] = *(const half8*)&fl[mi * 16 + lr][kt * 32 + lg * 8];
            }
            half8 bh[4], bl[4];
#pragma unroll
            for (int ni = 0; ni < 4; ++ni) {
                const float* src = W + (size_t)(w * 64 + ni * 16 + lr) * C + kt * 32 + lg * 8;
                const float4 x0 = *(const float4*)src;
                const float4 x1 = *(const float4*)(src + 4);
                const float xs[8] = {x0.x, x0.y, x0.z, x0.w, x1.x, x1.y, x1.z, x1.w};
#pragma unroll
                for (int e = 0; e < 8; ++e) {
                    const _Float16 h = (_Float16)xs[e];
                    bh[ni][e] = h;
                    bl[ni][e] = (_Float16)(xs[e] - (float)h);
                }
            }
#pragma unroll
            for (int mi = 0; mi < 2; ++mi)
#pragma unroll
                for (int ni = 0; ni < 4; ++ni) {
                    acc[mi][ni] = mfma16(ah[mi], bh[ni], acc[mi][ni]);
                    acc[mi][ni] = mfma16(ah[mi], bl[ni], acc[mi][ni]);
                    acc[mi][ni] = mfma16(al[mi], bh[ni], acc[mi][ni]);
                }
        }
        _Float16* dst = Od[qk];
#pragma unroll
        for (int mi = 0; mi < 2; ++mi)
#pragma unroll
            for (int ni = 0; ni < 4; ++ni)
#pragma unroll
                for (int r = 0; r < 4; ++r)
                    dst[(size_t)(n0 + mi * 16 + lg * 4 + r) * C + (w * 64 + ni * 16 + lr)] =
                        (_Float16)acc[mi][ni][r];
    }

    {
        f32x4 acc[4][2];
#pragma unroll
        for (int mi = 0; mi < 4; ++mi)
#pragma unroll
            for (int ni = 0; ni < 2; ++ni) acc[mi][ni] = (f32x4){0.f, 0.f, 0.f, 0.f};

#pragma unroll 1
        for (int kt = 0; kt < 8; ++kt) {
            half8 ah[4], al[4];
#pragma unroll
            for (int mi = 0; mi < 4; ++mi) {
                const float* src = Wv + (size_t)(w * 64 + mi * 16 + lr) * C + kt * 32 + lg * 8;
                const float4 x0 = *(const float4*)src;
                const float4 x1 = *(const float4*)(src + 4);
                const float xs[8] = {x0.x, x0.y, x0.z, x0.w, x1.x, x1.y, x1.z, x1.w};
#pragma unroll
                for (int e = 0; e < 8; ++e) {
                    const _Float16 h = (_Float16)xs[e];
                    ah[mi][e] = h;
                    al[mi][e] = (_Float16)(xs[e] - (float)h);
                }
            }
            half8 bh[2], bl[2];
#pragma unroll
            for (int ni = 0; ni < 2; ++ni) {
                bh[ni] = *(const half8*)&fh[ni * 16 + lr][kt * 32 + lg * 8];
                bl[ni] = *(const half8*)&fl[ni * 16 + lr][kt * 32 + lg * 8];
            }
#pragma unroll
            for (int mi = 0; mi < 4; ++mi)
#pragma unroll
                for (int ni = 0; ni < 2; ++ni) {
                    acc[mi][ni] = mfma16(ah[mi], bh[ni], acc[mi][ni]);
                    acc[mi][ni] = mfma16(ah[mi], bl[ni], acc[mi][ni]);
                    acc[mi][ni] = mfma16(al[mi], bh[ni], acc[mi][ni]);
                }
        }
        _Float16* vb = Vp + (size_t)b * C * NN;
#pragma unroll
        for (int mi = 0; mi < 4; ++mi)
#pragma unroll
            for (int ni = 0; ni < 2; ++ni)
#pragma unroll
                for (int r = 0; r < 4; ++r)
                    vb[(size_t)(w * 64 + mi * 16 + lg * 4 + r) * NN + n0 + ni * 16 + lr] =
                        (_Float16)acc[mi][ni][r];
    }
}

// ---------------------------------------------------------------------------
// Kernel 2: split-K flash attention. 8 waves/block, 32 query cols per wave,
// 32-key tiles double-buffered in LDS via global_load_lds with pre-swizzled
// sources (XOR bank swizzle). Partials (m, l, O/l in f16) per split.
// ---------------------------------------------------------------------------

// stage tile t into LDS buffer nb (K: 16KB, V: 16KB), bank-swizzled
#define STAGE(nb, t) do {                                                      \
    char* kd = (char*)&Kb_s[nb][0];                                            \
    char* vd = (char*)&Vb_s[nb][0];                                            \
    const char* kt_ = Ktile0 + (size_t)(t) * 16384;                            \
    const char* vt_ = Vtile0 + (size_t)(t) * 64;                               \
    { const int ub = w * 1024; const int a = ub + lane * 16;                   \
      gld16(kt_ + (a ^ (((a >> 9) & 7) << 4)), kd + ub);                       \
      gld16(vt_ + ((size_t)(a >> 6) * 8192 +                                   \
                   ((a & 63) ^ (((a >> 6) & 3) << 4))), vd + ub); }            \
    { const int ub = (8 + w) * 1024; const int a = ub + lane * 16;             \
      gld16(kt_ + (a ^ (((a >> 9) & 7) << 4)), kd + ub);                       \
      gld16(vt_ + ((size_t)(a >> 6) * 8192 +                                   \
                   ((a & 63) ^ (((a >> 6) & 3) << 4))), vd + ub); }            \
} while (0)

template<int KS>
__global__ __launch_bounds__(512, 2) void attn_split(
    const _Float16* __restrict__ Qt, const _Float16* __restrict__ Kt,
    const _Float16* __restrict__ Vp, _Float16* __restrict__ Opart,
    float* __restrict__ ml, float* __restrict__ out)
{
    const int lin = blockIdx.x;
    const int xcd = lin & 7, slot = lin >> 3;
    int b, ks, jt;
    if constexpr (KS == 4) {
        const int combo = xcd * 2 + (slot >> 4);
        b = combo >> 2; ks = combo & 3; jt = slot & 15;
    } else if constexpr (KS == 2) {
        b = xcd >> 1; ks = xcd & 1; jt = slot;
    } else {
        b = xcd >> 1; ks = 0; jt = (slot << 1) | (xcd & 1);
    }

    const int tid = threadIdx.x;
    const int w = tid >> 6, lane = tid & 63, lr = lane & 15, lg = lane >> 4;
    const int j0 = jt * 256 + w * 32;
    const int T = (NN / KS) / 32;
    const int iBase = ks * (NN / KS);

    __shared__ __align__(16) _Float16 Kb_s[2][32 * 256];   // 2 x 16KB
    __shared__ __align__(16) _Float16 Vb_s[2][256 * 32];   // 2 x 16KB
    __shared__ __align__(16) _Float16 Pb_s[8][1024];       // 16KB (wave-private)

    const _Float16* Qb = Qt + (size_t)b * NN * C;
    const char* Ktile0 = (const char*)(Kt + (size_t)b * NN * C + (size_t)iBase * C);
    const char* Vtile0 = (const char*)(Vp + (size_t)b * C * NN + iBase);

    // Q fragments: wave's 32 cols, all of C, resident in regs (64 VGPR)
    half8 q[2][8];
#pragma unroll
    for (int jn = 0; jn < 2; ++jn)
#pragma unroll
        for (int k8 = 0; k8 < 8; ++k8)
            q[jn][k8] = *(const half8*)(Qb + (size_t)(j0 + jn * 16 + lr) * C + k8 * 32 + lg * 8);

    f32x4 O[16][2];
#pragma unroll
    for (int oi = 0; oi < 16; ++oi) {
        O[oi][0] = (f32x4){0.f, 0.f, 0.f, 0.f};
        O[oi][1] = (f32x4){0.f, 0.f, 0.f, 0.f};
    }
    float m0 = -1e30f, m1 = -1e30f, l0 = 0.f, l1 = 0.f;

    const int kswzK = (lr & 7) << 4;   // 512B-row swizzle (K tile)
    const int kswzP = (lr & 3) << 4;   // 64B-row swizzle (V tile, P tile)

    STAGE(0, 0);
    __syncthreads();

    char* pw = (char*)&Pb_s[w][0];

#pragma unroll 1
    for (int t = 0; t < T; ++t) {
        const int cur = t & 1;
        if (t + 1 < T) STAGE(cur ^ 1, t + 1);

        // ---- S tile: S[i(32), j(32)] = sum_c K[i,c] Q[c,j]
        const char* kb = (const char*)&Kb_s[cur][0];
        f32x4 s00 = (f32x4){0,0,0,0}, s01 = (f32x4){0,0,0,0};
        f32x4 s10 = (f32x4){0,0,0,0}, s11 = (f32x4){0,0,0,0};
#pragma unroll
        for (int k8 = 0; k8 < 8; ++k8) {
            const int cb = (k8 * 64 + lg * 16) ^ kswzK;
            const half8 a0 = *(const half8*)(kb + lr * 512 + cb);
            const half8 a1 = *(const half8*)(kb + (16 + lr) * 512 + cb);
            s00 = mfma16(a0, q[0][k8], s00);
            s10 = mfma16(a0, q[1][k8], s10);
            s01 = mfma16(a1, q[0][k8], s01);
            s11 = mfma16(a1, q[1][k8], s11);
        }

        // ---- online softmax over keys, deferred rescale (tau=8)
        float tm0 = fmaxf(fmaxf(fmaxf(s00[0], s00[1]), fmaxf(s00[2], s00[3])),
                          fmaxf(fmaxf(s01[0], s01[1]), fmaxf(s01[2], s01[3])));
        float tm1 = fmaxf(fmaxf(fmaxf(s10[0], s10[1]), fmaxf(s10[2], s10[3])),
                          fmaxf(fmaxf(s11[0], s11[1]), fmaxf(s11[2], s11[3])));
        tm0 = fmaxf(tm0, __shfl_xor(tm0, 16, 64));
        tm0 = fmaxf(tm0, __shfl_xor(tm0, 32, 64));
        tm1 = fmaxf(tm1, __shfl_xor(tm1, 16, 64));
        tm1 = fmaxf(tm1, __shfl_xor(tm1, 32, 64));
        if (__any((tm0 > m0 + TAU) || (tm1 > m1 + TAU))) {
            const float mn0 = fmaxf(m0, tm0), mn1 = fmaxf(m1, tm1);
            const float sc0 = __expf(m0 - mn0), sc1 = __expf(m1 - mn1);
            l0 *= sc0; l1 *= sc1; m0 = mn0; m1 = mn1;
#pragma unroll
            for (int oi = 0; oi < 16; ++oi) { O[oi][0] *= sc0; O[oi][1] *= sc1; }
        }

        float ss0 = 0.f, ss1 = 0.f;
#pragma unroll
        for (int mi = 0; mi < 2; ++mi) {
            const f32x4 sv = mi ? s01 : s00;
            half4_t ph;
#pragma unroll
            for (int r = 0; r < 4; ++r) {
                const float p = __expf(sv[r] - m0); ss0 += p; ph[r] = (_Float16)p;
            }
            *(half4_t*)(pw + lr * 64 + ((mi * 32 + lg * 8) ^ kswzP)) = ph;
        }
#pragma unroll
        for (int mi = 0; mi < 2; ++mi) {
            const f32x4 sv = mi ? s11 : s10;
            half4_t ph;
#pragma unroll
            for (int r = 0; r < 4; ++r) {
                const float p = __expf(sv[r] - m1); ss1 += p; ph[r] = (_Float16)p;
            }
            *(half4_t*)(pw + (16 + lr) * 64 + ((mi * 32 + lg * 8) ^ kswzP)) = ph;
        }
        ss0 += __shfl_xor(ss0, 16, 64); ss0 += __shfl_xor(ss0, 32, 64); l0 += ss0;
        ss1 += __shfl_xor(ss1, 16, 64); ss1 += __shfl_xor(ss1, 32, 64); l1 += ss1;

        asm volatile("s_waitcnt lgkmcnt(0)" ::: "memory");
        __builtin_amdgcn_sched_barrier(0);

        // ---- PV: O[o(256), j(32)] += V[o, i] P[i, j]
        const half8 pf0 = *(const half8*)(pw + lr * 64 + ((lg * 16) ^ kswzP));
        const half8 pf1 = *(const half8*)(pw + (16 + lr) * 64 + ((lg * 16) ^ kswzP));
        const char* vb = (const char*)&Vb_s[cur][0];
#pragma unroll
        for (int oi = 0; oi < 16; ++oi) {
            const half8 vf = *(const half8*)(vb + (oi * 16 + lr) * 64 + ((lg * 16) ^ kswzP));
            O[oi][0] = mfma16(vf, pf0, O[oi][0]);
            O[oi][1] = mfma16(vf, pf1, O[oi][1]);
        }
        __syncthreads();
    }

    // ---- epilogue
    const float inv0 = 1.f / l0, inv1 = 1.f / l1;
    if constexpr (KS == 1) {
        float* ob = out + (size_t)b * 2 * C * NN;
#pragma unroll
        for (int oi = 0; oi < 16; ++oi)
#pragma unroll
            for (int r = 0; r < 4; ++r) {
                const int o = oi * 16 + lg * 4 + r;
                ob[(size_t)o * NN + j0 + lr]      = fmaxf(O[oi][0][r] * inv0, 0.f);
                ob[(size_t)o * NN + j0 + 16 + lr] = fmaxf(O[oi][1][r] * inv1, 0.f);
            }
    } else {
        _Float16* op = Opart + (size_t)(b * KS + ks) * C * NN;
#pragma unroll
        for (int oi = 0; oi < 16; ++oi)
#pragma unroll
            for (int r = 0; r < 4; ++r) {
                const int o = oi * 16 + lg * 4 + r;
                op[(size_t)o * NN + j0 + lr]      = (_Float16)(O[oi][0][r] * inv0);
                op[(size_t)o * NN + j0 + 16 + lr] = (_Float16)(O[oi][1][r] * inv1);
            }
        if (lg == 0) {
            float* mlb = ml + (size_t)(b * KS + ks) * 2 * NN;
            mlb[j0 + lr]          = m0;  mlb[j0 + 16 + lr]      = m1;
            mlb[NN + j0 + lr]     = l0;  mlb[NN + j0 + 16 + lr] = l1;
        }
    }
}

// ---------------------------------------------------------------------------
// Kernel 3: combine split-K partials: out = relu( sum_s w_s * Ohat_s ),
// w_s = exp(m_s - M) * l_s / L.
// ---------------------------------------------------------------------------
template<int KS>
__global__ __launch_bounds__(256) void combine_kernel(
    const _Float16* __restrict__ Opart, const float* __restrict__ ml,
    float* __restrict__ out)
{
    const int b = blockIdx.x >> 6, cc = blockIdx.x & 63;
    const int tid = threadIdx.x;
    const int col = cc * 64 + (tid & 63);
    const int op0 = tid >> 6;  // 0..3
    float mv[KS], wgt[KS];
    float M = -1e30f;
#pragma unroll
    for (int s = 0; s < KS; ++s) {
        mv[s] = ml[(size_t)(b * KS + s) * 2 * NN + col];
        M = fmaxf(M, mv[s]);
    }
    float L = 0.f;
#pragma unroll
    for (int s = 0; s < KS; ++s) {
        const float lv = ml[((size_t)(b * KS + s) * 2 + 1) * NN + col];
        wgt[s] = __expf(mv[s] - M) * lv; L += wgt[s];
    }
    const float invL = 1.f / L;
#pragma unroll
    for (int s = 0; s < KS; ++s) wgt[s] *= invL;
    float* ob = out + (size_t)b * 2 * C * NN + col;
    for (int oit = 0; oit < 64; ++oit) {
        const int o = oit * 4 + op0;
        float acc = 0.f;
#pragma unroll
        for (int s = 0; s < KS; ++s)
            acc += wgt[s] * (float)Opart[((size_t)(b * KS + s) * C + o) * NN + col];
        ob[(size_t)o * NN] = fmaxf(acc, 0.f);
    }
}

// ---------------------------------------------------------------------------
extern "C" void kernel_launch(void* const* d_in, const int* in_sizes, int n_in,
                              void* d_out, int out_size, void* d_ws, size_t ws_size,
                              hipStream_t stream) {
    const float* fea = (const float*)d_in[0];
    const float* Wq  = (const float*)d_in[1];
    const float* Wk  = (const float*)d_in[2];
    const float* Wv  = (const float*)d_in[3];
    float* out = (float*)d_out;

    _Float16* Qt = (_Float16*)d_ws;
    _Float16* Kt = Qt + (size_t)NB * NN * C;
    _Float16* Vp = Kt + (size_t)NB * NN * C;
    char* extra = (char*)(Vp + (size_t)NB * NN * C);           // +24MB
    const size_t base = (size_t)3 * NB * NN * C * sizeof(_Float16);

    proj_kernel<<<dim3(128, 4), 256, 0, stream>>>(fea, Wq, Wk, Wv, Qt, Kt, Vp, out);

    const size_t need4 = base + (size_t)4 * NB * C * NN * 2 + (size_t)4 * NB * 2 * NN * 4;
    const size_t need2 = base + (size_t)2 * NB * C * NN * 2 + (size_t)2 * NB * 2 * NN * 4;

    if (ws_size >= need4) {
        _Float16* Op = (_Float16*)extra;
        float* mlp = (float*)(extra + (size_t)4 * NB * C * NN * 2);
        attn_split<4><<<256, 512, 0, stream>>>(Qt, Kt, Vp, Op, mlp, out);
        combine_kernel<4><<<NB * 64, 256, 0, stream>>>(Op, mlp, out);
    } else if (ws_size >= need2) {
        _Float16* Op = (_Float16*)extra;
        float* mlp = (float*)(extra + (size_t)2 * NB * C * NN * 2);
        attn_split<2><<<128, 512, 0, stream>>>(Qt, Kt, Vp, Op, mlp, out);
        combine_kernel<2><<<NB * 64, 256, 0, stream>>>(Op, mlp, out);
    } else {
        attn_split<1><<<64, 512, 0, stream>>>(Qt, Kt, Vp, nullptr, nullptr, out);
    }
}